// Round 2
// baseline (137.141 us; speedup 1.0000x reference)
//
#include <hip/hip_runtime.h>

// B=4, C=256, CR=64, H=W=64, K=7, KK=49, GROUPS=16, GC=16
#define BN_EPS 1e-5f

typedef __bf16 bf16_t;
typedef __bf16 bf16x8 __attribute__((ext_vector_type(8)));
typedef __bf16 bf16x4 __attribute__((ext_vector_type(4)));
typedef __bf16 bf16x2 __attribute__((ext_vector_type(2)));
typedef float  floatx4 __attribute__((ext_vector_type(4)));

#define MFMA16(a, b, c) __builtin_amdgcn_mfma_f32_16x16x32_bf16((a), (b), (c), 0, 0, 0)

// ws layout: xT (16384 px x 64 ch bf16 = 2 MB) @ 0, wgG (784 x 16384 bf16 = 25.7 MB) @ 4 MB
#define XT_OFF 0
#define WG_OFF (4u << 20)

// ---------------------------------------------------------------------------
// K1 conv1: one block per (b,h), 512 threads. w1 A-frags direct from global
// (L2-hot) with BN fold in regs; guide transpose staged in LDS (33.8 KB).
// MFMA x[64o][64p]; +bias, ReLU; store xT[bp][o] (c-contiguous).
// ---------------------------------------------------------------------------
#define GTP 264

__global__ __launch_bounds__(512) void conv1_k(
    const float* __restrict__ guide, const float* __restrict__ w1,
    const float* __restrict__ gamma, const float* __restrict__ beta,
    const float* __restrict__ mean,  const float* __restrict__ var,
    bf16_t* __restrict__ xT)
{
    __shared__ __attribute__((aligned(16))) bf16_t gTs[64 * GTP];  // 33.8 KB
    const int b = blockIdx.x >> 6, h = blockIdx.x & 63;
    const int t = threadIdx.x;

    // stage guide row transposed: coalesced dword reads (lanes = p)
    const float* gsrc = guide + (size_t)b * 256 * 4096 + h * 64;
#pragma unroll
    for (int i = 0; i < 16; ++i) {
        const int idx = i * 512 + t;       // 8192 units = 128 c2 x 64 p
        const int c2 = idx >> 6, p = idx & 63;
        const float g0 = gsrc[(size_t)(2 * c2) * 4096 + p];
        const float g1 = gsrc[(size_t)(2 * c2 + 1) * 4096 + p];
        bf16x2 pk; pk[0] = (bf16_t)g0; pk[1] = (bf16_t)g1;
        *(bf16x2*)&gTs[p * GTP + 2 * c2] = pk;
    }
    __syncthreads();

    const int wv = t >> 6, ln = t & 63, l15 = ln & 15, q = ln >> 4;
    const int ot = wv & 3;          // o-tile: channels ot*16 .. +16
    const int ph = wv >> 2;         // p-half: pixels ph*32 .. +32
    const int o = ot * 16 + l15;    // A-row this lane reads
    const float iv = gamma[o] * rsqrtf(var[o] + BN_EPS);

    floatx4 acc[2] = {};
#pragma unroll
    for (int ks = 0; ks < 8; ++ks) {
        const float* wp = w1 + o * 256 + ks * 32 + q * 8;
        const float4 a0 = *(const float4*)(wp);
        const float4 a1 = *(const float4*)(wp + 4);
        bf16x8 a;
        a[0] = (bf16_t)(a0.x * iv); a[1] = (bf16_t)(a0.y * iv);
        a[2] = (bf16_t)(a0.z * iv); a[3] = (bf16_t)(a0.w * iv);
        a[4] = (bf16_t)(a1.x * iv); a[5] = (bf16_t)(a1.y * iv);
        a[6] = (bf16_t)(a1.z * iv); a[7] = (bf16_t)(a1.w * iv);
#pragma unroll
        for (int nt = 0; nt < 2; ++nt) {
            const bf16x8 bb = *(const bf16x8*)&gTs[(ph * 32 + nt * 16 + l15) * GTP + ks * 32 + q * 8];
            acc[nt] = MFMA16(a, bb, acc[nt]);
        }
    }
    float bi[4];
#pragma unroll
    for (int j = 0; j < 4; ++j) {
        const int o2 = ot * 16 + q * 4 + j;
        const float iv2 = gamma[o2] * rsqrtf(var[o2] + BN_EPS);
        bi[j] = beta[o2] - mean[o2] * iv2;
    }
#pragma unroll
    for (int nt = 0; nt < 2; ++nt) {
        const int p = ph * 32 + nt * 16 + l15;
        bf16x4 v;
#pragma unroll
        for (int j = 0; j < 4; ++j) v[j] = (bf16_t)fmaxf(acc[nt][j] + bi[j], 0.f);
        *(bf16x4*)(xT + ((size_t)(b * 64 + h) * 64 + p) * 64 + ot * 16 + q * 4) = v;
    }
}

// ---------------------------------------------------------------------------
// K2a conv2: one block = (g, b, h-pair), grid 2048, 256 thr.
// MFMA wg[49k x 128px] = w2[g].xT (A: fp32 w2 global->cvt in regs; B: direct
// global xT), +b2 -> wgs bf16 (13.3 KB LDS only -> 6+ blocks/CU), then
// coalesced flush wgs -> wgG[g*49+k][p] (256 B per k-row).
// ---------------------------------------------------------------------------
#define WGP 136

__global__ __launch_bounds__(256) void conv2_k(
    const bf16_t* __restrict__ xT, const float* __restrict__ w2,
    const float* __restrict__ b2,  bf16_t* __restrict__ wgG)
{
    __shared__ __attribute__((aligned(16))) bf16_t wgs[49 * WGP];  // 13.3 KB

    const int g = blockIdx.x & 15;
    const int rest = blockIdx.x >> 4;      // 0..127
    const int b = rest >> 5, hp = rest & 31;
    const int h0 = hp * 2;
    const int t = threadIdx.x;
    const int wv = t >> 6, ln = t & 63, l15 = ln & 15, q = ln >> 4;

    {
        floatx4 acc[4][2] = {};
        const bf16_t* brow = xT + ((size_t)(b * 64 + h0) * 64 + wv * 32) * 64;
#pragma unroll
        for (int ks = 0; ks < 2; ++ks) {
            bf16x8 bfr[2];
            bfr[0] = *(const bf16x8*)(brow + l15 * 64 + ks * 32 + q * 8);
            bfr[1] = *(const bf16x8*)(brow + (16 + l15) * 64 + ks * 32 + q * 8);
#pragma unroll
            for (int mt = 0; mt < 4; ++mt) {
                int row = mt * 16 + l15; if (row > 48) row = 48;  // pad rows never stored
                const float* wp = w2 + (size_t)(g * 49 + row) * 64 + ks * 32 + q * 8;
                const float4 a0 = *(const float4*)(wp);
                const float4 a1 = *(const float4*)(wp + 4);
                bf16x8 a;
                a[0] = (bf16_t)a0.x; a[1] = (bf16_t)a0.y; a[2] = (bf16_t)a0.z; a[3] = (bf16_t)a0.w;
                a[4] = (bf16_t)a1.x; a[5] = (bf16_t)a1.y; a[6] = (bf16_t)a1.z; a[7] = (bf16_t)a1.w;
                acc[mt][0] = MFMA16(a, bfr[0], acc[mt][0]);
                acc[mt][1] = MFMA16(a, bfr[1], acc[mt][1]);
            }
        }
#pragma unroll
        for (int mt = 0; mt < 4; ++mt) {
#pragma unroll
            for (int j = 0; j < 4; ++j) {
                const int k = mt * 16 + q * 4 + j;
                if (k < 49) {
                    const float bias = b2[g * 49 + k];
                    wgs[k * WGP + wv * 32 + l15]      = (bf16_t)(acc[mt][0][j] + bias);
                    wgs[k * WGP + wv * 32 + 16 + l15] = (bf16_t)(acc[mt][1][j] + bias);
                }
            }
        }
    }
    __syncthreads();

    // flush: 49 k x 128 px bf16 = 1568 units of 8B; coalesced 256 B per k-row
    const size_t obase = (size_t)(g * 49) * 16384 + (size_t)(b * 64 + h0) * 64;
#pragma unroll
    for (int i = 0; i < 7; ++i) {
        const int u = i * 256 + t;
        if (u < 1568) {
            const int k = u >> 5, j = u & 31;
            *(bf16x4*)(wgG + obase + (size_t)k * 16384 + j * 4) =
                *(const bf16x4*)&wgs[k * WGP + j * 4];
        }
    }
}

// ---------------------------------------------------------------------------
// K2b agg: one block = (g, b, h-quad), grid 1024, 512 thr.
// LDS = fs only (16ch x 10 rows x 72, 46 KB -> 3 blocks/CU = 24 waves/CU).
// Single barrier; agg reads per-tap weights DIRECT from global wgG: one
// contiguous 512 B line per (di,dj) per wave, block slice (25 KB) L1-resident.
// thread = (wq, r in 0..3, cp) -> 2ch x 4w; residual from fs fp32; f4 stores.
// ---------------------------------------------------------------------------
#define FSR 72      // fs row pitch (floats): [4 pad][64 w][4 pad]
#define FSC 720     // fs channel pitch = 10*72

__global__ __launch_bounds__(512, 6) void agg_k(
    const bf16_t* __restrict__ wgG, const float* __restrict__ feat,
    float* __restrict__ out)
{
    __shared__ __attribute__((aligned(16))) float fs[16 * FSC];   // 46.1 KB

    const int g = blockIdx.x & 15;
    const int rest = blockIdx.x >> 4;      // 0..63
    const int b = rest >> 4, hq = rest & 15;
    const int h0 = hq * 4;
    const int t = threadIdx.x;

    // ---- stage fs: 16 ch x 10 rows x 18 quads = 2880 quads, zero-padded ----
#pragma unroll
    for (int i = 0; i < 6; ++i) {
        const int u = i * 512 + t;
        if (u < 2880) {
            const int c = u / 180, rem = u - c * 180;
            const int rr = rem / 18, qq = rem - rr * 18;
            const int hh = h0 - 3 + rr;
            float4 v = {0.f, 0.f, 0.f, 0.f};
            if (qq >= 1 && qq <= 16 && hh >= 0 && hh < 64)
                v = *(const float4*)(feat + ((size_t)(b * 256 + g * 16 + c) * 64 + hh) * 64 + (qq - 1) * 4);
            *(float4*)&fs[c * FSC + rr * FSR + qq * 4] = v;
        }
    }
    __syncthreads();

    // ---- agg: thread = (wq, r, cp) -> 2 ch x 4 w ----
    const int wq = t & 15, r = (t >> 4) & 3, cp = t >> 6;   // cp in [0,8)
    const int w0 = wq * 4;
    const int ch0 = cp * 2;

    float acc[2][4] = {};
    const bf16_t* wbase = wgG + (size_t)(g * 49) * 16384
                              + (size_t)(b * 64 + h0 + r) * 64 + w0;
#pragma unroll
    for (int di = 0; di < 7; ++di) {
        const int ri = r + di;             // 0..9, zero-padded rows
        float f0[12], f1[12];
        {
            const float* p0 = &fs[ch0 * FSC + ri * FSR + w0];
            const float* p1 = p0 + FSC;
#pragma unroll
            for (int qj = 0; qj < 3; ++qj) {
                const floatx4 a = *(const floatx4*)(p0 + qj * 4);
                const floatx4 bq = *(const floatx4*)(p1 + qj * 4);
#pragma unroll
                for (int j = 0; j < 4; ++j) { f0[qj * 4 + j] = a[j]; f1[qj * 4 + j] = bq[j]; }
            }
        }
        const bf16_t* wrow = wbase + (size_t)(di * 7) * 16384;
#pragma unroll
        for (int dj = 0; dj < 7; ++dj) {
            const bf16x4 wb = *(const bf16x4*)(wrow + (size_t)dj * 16384);
#pragma unroll
            for (int x = 0; x < 4; ++x) {
                const float wf = (float)wb[x];
                acc[0][x] = fmaf(wf, f0[x + dj + 1], acc[0][x]);
                acc[1][x] = fmaf(wf, f1[x + dj + 1], acc[1][x]);
            }
        }
    }

    // residual from staged fp32 tile (row r+3 == h0+r), + store
#pragma unroll
    for (int c = 0; c < 2; ++c) {
        const floatx4 res = *(const floatx4*)&fs[(ch0 + c) * FSC + (r + 3) * FSR + 4 + w0];
        const size_t ob = ((size_t)(b * 256 + g * 16 + ch0 + c) * 64 + h0 + r) * 64 + w0;
        float4 o;
        o.x = acc[c][0] + res[0]; o.y = acc[c][1] + res[1];
        o.z = acc[c][2] + res[2]; o.w = acc[c][3] + res[3];
        *(float4*)(out + ob) = o;
    }
}

extern "C" void kernel_launch(void* const* d_in, const int* in_sizes, int n_in,
                              void* d_out, int out_size, void* d_ws, size_t ws_size,
                              hipStream_t stream) {
    const float* feature = (const float*)d_in[0];
    const float* guide   = (const float*)d_in[1];
    const float* w1      = (const float*)d_in[2];
    const float* gamma   = (const float*)d_in[3];
    const float* beta    = (const float*)d_in[4];
    const float* mean    = (const float*)d_in[5];
    const float* var     = (const float*)d_in[6];
    const float* w2      = (const float*)d_in[7];
    const float* b2      = (const float*)d_in[8];
    float* out = (float*)d_out;

    bf16_t* xT  = (bf16_t*)((char*)d_ws + XT_OFF);
    bf16_t* wgG = (bf16_t*)((char*)d_ws + WG_OFF);

    conv1_k<<<256, 512, 0, stream>>>(guide, w1, gamma, beta, mean, var, xT);
    conv2_k<<<2048, 256, 0, stream>>>(xT, w2, b2, wgG);
    agg_k<<<1024, 512, 0, stream>>>(wgG, feature, out);
}

// Round 3
// 135.569 us; speedup vs baseline: 1.0116x; 1.0116x over previous
//
#include <hip/hip_runtime.h>

// B=4, C=256, CR=64, H=W=64, K=7, KK=49, GROUPS=16, GC=16
#define BN_EPS 1e-5f

typedef __bf16 bf16_t;
typedef __bf16 bf16x8 __attribute__((ext_vector_type(8)));
typedef __bf16 bf16x4 __attribute__((ext_vector_type(4)));
typedef __bf16 bf16x2 __attribute__((ext_vector_type(2)));
typedef float  floatx4 __attribute__((ext_vector_type(4)));

#define MFMA16(a, b, c) __builtin_amdgcn_mfma_f32_16x16x32_bf16((a), (b), (c), 0, 0, 0)

// ws layout: only xT (16384 px x 64 ch bf16 = 2 MB)
#define XT_OFF 0

// ---------------------------------------------------------------------------
// K1 conv1: one block per (b,h), 512 threads (2 waves/SIMD). w1 A-frags direct
// from global (L2-hot) with BN fold in regs; guide transpose staged in LDS.
// MFMA x[64o][64p]; +bias, ReLU; store xT[bp][o] (c-contiguous).
// ---------------------------------------------------------------------------
#define GTP 264

__global__ __launch_bounds__(512) void conv1_k(
    const float* __restrict__ guide, const float* __restrict__ w1,
    const float* __restrict__ gamma, const float* __restrict__ beta,
    const float* __restrict__ mean,  const float* __restrict__ var,
    bf16_t* __restrict__ xT)
{
    __shared__ __attribute__((aligned(16))) bf16_t gTs[64 * GTP];  // 33.8 KB
    const int b = blockIdx.x >> 6, h = blockIdx.x & 63;
    const int t = threadIdx.x;

    // stage guide row transposed: coalesced dword reads (lanes = p)
    const float* gsrc = guide + (size_t)b * 256 * 4096 + h * 64;
#pragma unroll
    for (int i = 0; i < 16; ++i) {
        const int idx = i * 512 + t;       // 8192 units = 128 c2 x 64 p
        const int c2 = idx >> 6, p = idx & 63;
        const float g0 = gsrc[(size_t)(2 * c2) * 4096 + p];
        const float g1 = gsrc[(size_t)(2 * c2 + 1) * 4096 + p];
        bf16x2 pk; pk[0] = (bf16_t)g0; pk[1] = (bf16_t)g1;
        *(bf16x2*)&gTs[p * GTP + 2 * c2] = pk;
    }
    __syncthreads();

    const int wv = t >> 6, ln = t & 63, l15 = ln & 15, q = ln >> 4;
    const int ot = wv & 3;          // o-tile: channels ot*16 .. +16
    const int ph = wv >> 2;         // p-half: pixels ph*32 .. +32
    const int o = ot * 16 + l15;    // A-row this lane reads
    const float iv = gamma[o] * rsqrtf(var[o] + BN_EPS);

    floatx4 acc[2] = {};
#pragma unroll
    for (int ks = 0; ks < 8; ++ks) {
        const float* wp = w1 + o * 256 + ks * 32 + q * 8;
        const float4 a0 = *(const float4*)(wp);
        const float4 a1 = *(const float4*)(wp + 4);
        bf16x8 a;
        a[0] = (bf16_t)(a0.x * iv); a[1] = (bf16_t)(a0.y * iv);
        a[2] = (bf16_t)(a0.z * iv); a[3] = (bf16_t)(a0.w * iv);
        a[4] = (bf16_t)(a1.x * iv); a[5] = (bf16_t)(a1.y * iv);
        a[6] = (bf16_t)(a1.z * iv); a[7] = (bf16_t)(a1.w * iv);
#pragma unroll
        for (int nt = 0; nt < 2; ++nt) {
            const bf16x8 bb = *(const bf16x8*)&gTs[(ph * 32 + nt * 16 + l15) * GTP + ks * 32 + q * 8];
            acc[nt] = MFMA16(a, bb, acc[nt]);
        }
    }
    float bi[4];
#pragma unroll
    for (int j = 0; j < 4; ++j) {
        const int o2 = ot * 16 + q * 4 + j;
        const float iv2 = gamma[o2] * rsqrtf(var[o2] + BN_EPS);
        bi[j] = beta[o2] - mean[o2] * iv2;
    }
#pragma unroll
    for (int nt = 0; nt < 2; ++nt) {
        const int p = ph * 32 + nt * 16 + l15;
        bf16x4 v;
#pragma unroll
        for (int j = 0; j < 4; ++j) v[j] = (bf16_t)fmaxf(acc[nt][j] + bi[j], 0.f);
        *(bf16x4*)(xT + ((size_t)(b * 64 + h) * 64 + p) * 64 + ot * 16 + q * 4) = v;
    }
}

// ---------------------------------------------------------------------------
// K2 conv2+agg fused, 1-ROW blocks: block = (g, b, h); blockIdx = (b*64+h)*16+g
// (XCD = g%8 -> per-XCD feat slice ~2.1 MB, L2-resident).
//  Parallel before single barrier:
//   - stage fs[16ch][7 rows][72 w] fp32, zero-padded borders (32.3 KB)
//   - MFMA wg[49k x 64px] = w2[g].xT (A: fp32 w2 global->cvt in regs;
//     B: direct global xT), +b2 -> wgs bf16 (7.1 KB)
//  barrier
//   - agg: thread = (wq, cp) -> 1ch x 4w; 196 FMA from LDS; fp32 residual
//     from fs; coalesced float4 stores.
// LDS 39.4 KB -> 4 blocks/CU (16 waves/CU). Grid 4096, short per-block chain.
// ---------------------------------------------------------------------------
#define FSR 72     // fs row pitch (floats): [4 pad][64 w][4 pad]
#define FSC 504    // fs channel pitch = 7*72
#define WGP 72     // wgs row pitch (bf16)

__global__ __launch_bounds__(256) void fused_k(
    const bf16_t* __restrict__ xT, const float* __restrict__ w2,
    const float* __restrict__ b2,  const float* __restrict__ feat,
    float* __restrict__ out)
{
    __shared__ __attribute__((aligned(16))) float  fs[16 * FSC];   // 32.3 KB
    __shared__ __attribute__((aligned(16))) bf16_t wgs[49 * WGP];  // 7.1 KB

    const int g = blockIdx.x & 15;
    const int rest = blockIdx.x >> 4;      // 0..255
    const int b = rest >> 6, h = rest & 63;
    const int t = threadIdx.x;
    const int wv = t >> 6, ln = t & 63, l15 = ln & 15, q = ln >> 4;

    // ---- stage fs: 16 ch x 7 rows x 18 quads = 2016 quads, zero-padded ----
#pragma unroll
    for (int i = 0; i < 8; ++i) {
        const int u = i * 256 + t;
        if (u < 2016) {
            const int c = u / 126, rem = u - c * 126;
            const int rr = rem / 18, qq = rem - rr * 18;
            const int hh = h - 3 + rr;
            float4 v = {0.f, 0.f, 0.f, 0.f};
            if (qq >= 1 && qq <= 16 && hh >= 0 && hh < 64)
                v = *(const float4*)(feat + ((size_t)(b * 256 + g * 16 + c) * 64 + hh) * 64 + (qq - 1) * 4);
            *(float4*)&fs[c * FSC + rr * FSR + qq * 4] = v;
        }
    }

    // ---- MFMA: wg[49 x 64] = w2[g] . xT_row ; wave wv = k-tile, all 4 px-tiles ----
    {
        floatx4 acc[4] = {};
        const bf16_t* brow = xT + ((size_t)(b * 64 + h) * 64) * 64;
        int row = wv * 16 + l15; if (row > 48) row = 48;   // pad rows never stored
#pragma unroll
        for (int ks = 0; ks < 2; ++ks) {
            const float* wp = w2 + (size_t)(g * 49 + row) * 64 + ks * 32 + q * 8;
            const float4 a0 = *(const float4*)(wp);
            const float4 a1 = *(const float4*)(wp + 4);
            bf16x8 a;
            a[0] = (bf16_t)a0.x; a[1] = (bf16_t)a0.y; a[2] = (bf16_t)a0.z; a[3] = (bf16_t)a0.w;
            a[4] = (bf16_t)a1.x; a[5] = (bf16_t)a1.y; a[6] = (bf16_t)a1.z; a[7] = (bf16_t)a1.w;
#pragma unroll
            for (int nt = 0; nt < 4; ++nt) {
                const bf16x8 bb = *(const bf16x8*)(brow + (nt * 16 + l15) * 64 + ks * 32 + q * 8);
                acc[nt] = MFMA16(a, bb, acc[nt]);
            }
        }
#pragma unroll
        for (int j = 0; j < 4; ++j) {
            const int k = wv * 16 + q * 4 + j;
            if (k < 49) {
                const float bias = b2[g * 49 + k];
#pragma unroll
                for (int nt = 0; nt < 4; ++nt)
                    wgs[k * WGP + nt * 16 + l15] = (bf16_t)(acc[nt][j] + bias);
            }
        }
    }
    __syncthreads();

    // ---- agg: thread = (wq, cp) -> 1 ch x 4 w, branchless ----
    const int wq = t & 15, cp = t >> 4;    // cp in [0,16)
    const int w0 = wq * 4;

    float acc4[4] = {};
#pragma unroll
    for (int di = 0; di < 7; ++di) {
        float f0[12];
        {
            const float* p0 = &fs[cp * FSC + di * FSR + w0];
#pragma unroll
            for (int qj = 0; qj < 3; ++qj) {
                const floatx4 a = *(const floatx4*)(p0 + qj * 4);
#pragma unroll
                for (int j = 0; j < 4; ++j) f0[qj * 4 + j] = a[j];
            }
        }
        const bf16_t* wrow = &wgs[(di * 7) * WGP + w0];
#pragma unroll
        for (int dj = 0; dj < 7; ++dj) {
            const bf16x4 wb = *(const bf16x4*)(wrow + dj * WGP);
#pragma unroll
            for (int x = 0; x < 4; ++x)
                acc4[x] = fmaf((float)wb[x], f0[x + dj + 1], acc4[x]);
        }
    }

    // residual from staged fp32 tile (row 3 == h), + store
    {
        const floatx4 res = *(const floatx4*)&fs[cp * FSC + 3 * FSR + 4 + w0];
        const size_t ob = ((size_t)(b * 256 + g * 16 + cp) * 64 + h) * 64 + w0;
        float4 o;
        o.x = acc4[0] + res[0]; o.y = acc4[1] + res[1];
        o.z = acc4[2] + res[2]; o.w = acc4[3] + res[3];
        *(float4*)(out + ob) = o;
    }
}

extern "C" void kernel_launch(void* const* d_in, const int* in_sizes, int n_in,
                              void* d_out, int out_size, void* d_ws, size_t ws_size,
                              hipStream_t stream) {
    const float* feature = (const float*)d_in[0];
    const float* guide   = (const float*)d_in[1];
    const float* w1      = (const float*)d_in[2];
    const float* gamma   = (const float*)d_in[3];
    const float* beta    = (const float*)d_in[4];
    const float* mean    = (const float*)d_in[5];
    const float* var     = (const float*)d_in[6];
    const float* w2      = (const float*)d_in[7];
    const float* b2      = (const float*)d_in[8];
    float* out = (float*)d_out;

    bf16_t* xT = (bf16_t*)((char*)d_ws + XT_OFF);

    conv1_k<<<256, 512, 0, stream>>>(guide, w1, gamma, beta, mean, var, xT);
    fused_k<<<4096, 256, 0, stream>>>(xT, w2, b2, feature, out);
}